// Round 1
// baseline (274.377 us; speedup 1.0000x reference)
//
#include <hip/hip_runtime.h>

// LinearAttention: N=8, L=S=4096, H=8, D=M=64, fp32.
// phase1 (4 s-splits): per-wave-private LDS tiles, each wave accumulates the FULL
//   64x64 (d,m) plane over its own 256 s-rows (per-lane 8x8 = 64 acc VGPRs).
//   4 ds_read_b128 per 64 FMAs (2x the FMA/LDS-read of the previous quadrant design),
//   each s-row read by exactly one wave, and NO __syncthreads in the main loop
//   (buffers are wave-private; in-wave waitcnts suffice). Cross-wave reduce at end.
// reduce: KVt = sum_sp KVp ; Ksum = sum_sp Ksump  (4 splits, 4 MB)
// phase2: 512-thread blocks, 512 Q-rows staged once; per-lane 16 rows x 4 m
//   (acc 64 VGPR, 21 LDS reads / 320 FMAs). Memory-bound by Q read + out write.

#define SLEN 4096
#define LLEN 4096
#define NHTOT 64      // N*H
#define HD   512      // H*D row stride in elements
#define NSPLIT 4
#define EPSF 1e-6f

__device__ __forceinline__ float phi(float x) {
    return x > 0.0f ? x + 1.0f : __expf(x);
}

__device__ __forceinline__ void fma4(float4& a, float s, const float4& b) {
    a.x = fmaf(s, b.x, a.x);
    a.y = fmaf(s, b.y, a.y);
    a.z = fmaf(s, b.z, a.z);
    a.w = fmaf(s, b.w, a.w);
}

// ---------------- Phase 1: per-split KV partials ----------------
// grid (NSPLIT=4, 64), block 256 = 4 waves, 1 block/CU (128 KB LDS).
// Each wave: 4 tiles of 64 s-rows -> private kb/vb [64][64]; full-plane acc.
__global__ __launch_bounds__(256)
void la_phase1(const float* __restrict__ Kg, const float* __restrict__ Vg,
               const float* __restrict__ maskg,
               float* __restrict__ KVp, float* __restrict__ Ksump) {
    __shared__ float kb[4][4096];    // per-wave phi(K)*mask tile, 64 KB total
    __shared__ float vb[4][4096];    // per-wave V tile, 64 KB total
    __shared__ float ksb[16 * 64];   // ksum partials (4 KB) -> 132 KB total

    const int tid  = threadIdx.x;
    const int w    = tid >> 6;
    const int lane = tid & 63;
    const int nh   = blockIdx.y;
    const int n    = nh >> 3;
    const int h    = nh & 7;
    const int sp   = blockIdx.x;

    // staging role: 4 rows x 16 chunks per u-iter (256 B contiguous per row)
    const int sr4 = lane >> 4;          // 0..3
    const int c4  = (lane & 15) * 4;    // float column
    // compute role: per-lane 8x8 tile of the full 64x64 plane
    const int d0  = (lane & 7) * 8;
    const int m0  = (lane >> 3) * 8;

    float* kw = kb[w];
    float* vw = vb[w];

    const size_t base = (size_t)n * SLEN * HD + (size_t)h * 64;
    const float* mrow = maskg + (size_t)n * SLEN;

    float4 acc[8][2];
    #pragma unroll
    for (int i = 0; i < 8; ++i) {
        acc[i][0] = make_float4(0.f, 0.f, 0.f, 0.f);
        acc[i][1] = make_float4(0.f, 0.f, 0.f, 0.f);
    }
    float4 ksp = make_float4(0.f, 0.f, 0.f, 0.f);

    for (int t = 0; t < 4; ++t) {
        const int srow0 = sp * 1024 + t * 256 + w * 64;
        // ---- stage this wave's 64 rows (phi+mask on K, ksum partial) ----
        #pragma unroll
        for (int u = 0; u < 16; ++u) {
            const int row = sr4 + u * 4;
            const int s   = srow0 + row;
            const size_t g = base + (size_t)s * HD + c4;
            float4 kf = *(const float4*)(Kg + g);
            const float4 vf = *(const float4*)(Vg + g);
            const float mm = mrow[s];
            kf.x = phi(kf.x) * mm;
            kf.y = phi(kf.y) * mm;
            kf.z = phi(kf.z) * mm;
            kf.w = phi(kf.w) * mm;
            ksp.x += kf.x; ksp.y += kf.y; ksp.z += kf.z; ksp.w += kf.w;
            *(float4*)&kw[row * 64 + c4] = kf;
            *(float4*)&vw[row * 64 + c4] = vf;
        }
        // ---- full-plane outer product over 64 s-rows (wave-private, no barrier) ----
        #pragma unroll 4
        for (int s = 0; s < 64; ++s) {
            const float4 ka = *(const float4*)&kw[s * 64 + d0];
            const float4 kz = *(const float4*)&kw[s * 64 + d0 + 4];
            const float4 va = *(const float4*)&vw[s * 64 + m0];
            const float4 vz = *(const float4*)&vw[s * 64 + m0 + 4];
            fma4(acc[0][0], ka.x, va); fma4(acc[0][1], ka.x, vz);
            fma4(acc[1][0], ka.y, va); fma4(acc[1][1], ka.y, vz);
            fma4(acc[2][0], ka.z, va); fma4(acc[2][1], ka.z, vz);
            fma4(acc[3][0], ka.w, va); fma4(acc[3][1], ka.w, vz);
            fma4(acc[4][0], kz.x, va); fma4(acc[4][1], kz.x, vz);
            fma4(acc[5][0], kz.y, va); fma4(acc[5][1], kz.y, vz);
            fma4(acc[6][0], kz.z, va); fma4(acc[6][1], kz.z, vz);
            fma4(acc[7][0], kz.w, va); fma4(acc[7][1], kz.w, vz);
        }
    }

    // ---- ksum partials to LDS ----
    *(float4*)&ksb[(w * 4 + sr4) * 64 + c4] = ksp;

    // ---- each wave parks its plane in its own kb region, then block-reduce ----
    #pragma unroll
    for (int di = 0; di < 8; ++di) {
        *(float4*)&kw[(d0 + di) * 64 + m0]     = acc[di][0];
        *(float4*)&kw[(d0 + di) * 64 + m0 + 4] = acc[di][1];
    }
    __syncthreads();

    float* outp = KVp + ((size_t)sp * NHTOT + nh) * 4096;
    #pragma unroll
    for (int j = 0; j < 4; ++j) {
        const int f = (j * 256 + tid) * 4;
        float4 a  = *(const float4*)&kb[0][f];
        const float4 b1 = *(const float4*)&kb[1][f];
        const float4 b2 = *(const float4*)&kb[2][f];
        const float4 b3 = *(const float4*)&kb[3][f];
        a.x += b1.x + b2.x + b3.x;
        a.y += b1.y + b2.y + b3.y;
        a.z += b1.z + b2.z + b3.z;
        a.w += b1.w + b2.w + b3.w;
        *(float4*)&outp[f] = a;
    }
    if (tid < 64) {
        float ssum = 0.f;
        #pragma unroll
        for (int r = 0; r < 16; ++r) ssum += ksb[r * 64 + tid];
        Ksump[((size_t)sp * NHTOT + nh) * 64 + tid] = ssum;
    }
}

// ---------------- Reduce: sum the 4 split partials ----------------
// grid 64 (one per nh), block 256
__global__ __launch_bounds__(256)
void la_reduce(const float* __restrict__ KVp, const float* __restrict__ Ksump,
               float* __restrict__ KVt, float* __restrict__ Ksum) {
    const int nh  = blockIdx.x;
    const int tid = threadIdx.x;
    #pragma unroll
    for (int j = 0; j < 4; ++j) {
        const int f = (j * 256 + tid) * 4;
        float4 a = make_float4(0.f, 0.f, 0.f, 0.f);
        #pragma unroll
        for (int s = 0; s < NSPLIT; ++s) {
            const float4 v = *(const float4*)&KVp[((size_t)s * NHTOT + nh) * 4096 + f];
            a.x += v.x; a.y += v.y; a.z += v.z; a.w += v.w;
        }
        *(float4*)&KVt[(size_t)nh * 4096 + f] = a;
    }
    if (tid < 64) {
        float a = 0.f;
        #pragma unroll
        for (int s = 0; s < NSPLIT; ++s)
            a += Ksump[((size_t)s * NHTOT + nh) * 64 + tid];
        Ksum[nh * 64 + tid] = a;
    }
}

// ---------------- Phase 2: out = phi(Q) @ KVt, normalized ----------------
// grid (L/512, 64), block 512 = 8 waves, 1 block/CU (152 KB LDS).
// Wave owns 64 rows; per-lane 16 rows (stride 4) x 4 consecutive m.
__global__ __launch_bounds__(512)
void la_phase2(const float* __restrict__ Qg, const float* __restrict__ KVt,
               const float* __restrict__ Ksum, float* __restrict__ Og) {
    __shared__ float Qs[512 * 68];  // 136 KiB, pad 68 keeps stride-4-row reads conflict-free
    __shared__ float KVs[64 * 64];  // 16 KiB
    __shared__ float KSs[64];       // total ~152 KiB -> 1 block/CU, 8 waves

    const int tid = threadIdx.x;    // 0..511
    const int nh  = blockIdx.y;
    const int n   = nh >> 3;
    const int h   = nh & 7;
    const int lbase = blockIdx.x * 512;

    // ---- stage KV + Ksum (L2-hot, coalesced) ----
    #pragma unroll
    for (int j = 0; j < 2; ++j) {
        const int f = (j * 512 + tid) * 4;
        *(float4*)&KVs[f] = *(const float4*)&KVt[(size_t)nh * 4096 + f];
    }
    if (tid < 16) *(float4*)&KSs[tid * 4] = *(const float4*)&Ksum[nh * 64 + tid * 4];

    // ---- stage phi(Q): 512 rows ----
    const int sr = tid >> 4;           // 0..31
    const int c4 = (tid & 15) * 4;
    #pragma unroll
    for (int u = 0; u < 16; ++u) {
        const int row = sr + u * 32;
        float4 q = *(const float4*)&Qg[((size_t)(n * LLEN + lbase + row) * 8 + h) * 64 + c4];
        q.x = phi(q.x); q.y = phi(q.y); q.z = phi(q.z); q.w = phi(q.w);
        *(float4*)&Qs[row * 68 + c4] = q;
    }
    __syncthreads();

    const int w    = tid >> 6;        // wave -> 64-row band
    const int lane = tid & 63;
    const int ty   = lane >> 4;       // 0..3
    const int tx   = lane & 15;
    const int m0   = tx * 4;
    const int rb   = w * 64 + ty;     // rows rb + 4*i, i<16

    float4 acc[16];
    float  den[16];
    #pragma unroll
    for (int i = 0; i < 16; ++i) {
        acc[i] = make_float4(0.f, 0.f, 0.f, 0.f);
        den[i] = 0.f;
    }

    for (int d4 = 0; d4 < 16; ++d4) {
        const float4 ks = *(const float4*)&KSs[d4 * 4];
        float4 q4[16];
        #pragma unroll
        for (int i = 0; i < 16; ++i)
            q4[i] = *(const float4*)&Qs[(rb + 4 * i) * 68 + d4 * 4];
        #pragma unroll
        for (int i = 0; i < 16; ++i) {
            den[i] = fmaf(q4[i].x, ks.x, den[i]);
            den[i] = fmaf(q4[i].y, ks.y, den[i]);
            den[i] = fmaf(q4[i].z, ks.z, den[i]);
            den[i] = fmaf(q4[i].w, ks.w, den[i]);
        }
        #pragma unroll
        for (int dk = 0; dk < 4; ++dk) {
            const float4 kv = *(const float4*)&KVs[(d4 * 4 + dk) * 64 + m0];
            #pragma unroll
            for (int i = 0; i < 16; ++i)
                fma4(acc[i], (&q4[i].x)[dk], kv);
        }
    }

    // ---- normalize + store ----
    #pragma unroll
    for (int i = 0; i < 16; ++i) {
        const int l = lbase + rb + 4 * i;
        const float z = 1.0f / (den[i] + EPSF);
        float4 o = acc[i];
        o.x *= z; o.y *= z; o.z *= z; o.w *= z;
        *(float4*)&Og[((size_t)(n * LLEN + l) * 8 + h) * 64 + m0] = o;
    }
}

extern "C" void kernel_launch(void* const* d_in, const int* in_sizes, int n_in,
                              void* d_out, int out_size, void* d_ws, size_t ws_size,
                              hipStream_t stream) {
    const float* Q    = (const float*)d_in[0];
    const float* K    = (const float*)d_in[1];
    const float* V    = (const float*)d_in[2];
    const float* mask = (const float*)d_in[3];
    float* out = (float*)d_out;

    float* KVp   = (float*)d_ws;                                  // [4][64][4096] = 4 MB
    float* Ksump = KVp + (size_t)NSPLIT * NHTOT * 4096;           // [4][64][64]
    float* KVt   = Ksump + (size_t)NSPLIT * NHTOT * 64;           // [64][4096]
    float* Ksum  = KVt + (size_t)NHTOT * 4096;                    // [64][64]
    // every ws element read is written first (no memset needed)

    dim3 g1(NSPLIT, NHTOT);
    la_phase1<<<g1, 256, 0, stream>>>(K, V, mask, KVp, Ksump);

    la_reduce<<<NHTOT, 256, 0, stream>>>(KVp, Ksump, KVt, Ksum);

    dim3 g2(LLEN / 512, NHTOT);
    la_phase2<<<g2, 512, 0, stream>>>(Q, KVt, Ksum, out);
}

// Round 2
// 262.076 us; speedup vs baseline: 1.0469x; 1.0469x over previous
//
#include <hip/hip_runtime.h>

// LinearAttention: N=8, L=S=4096, H=8, D=M=64, fp32.
// phase1 (8 s-splits): per-wave-private 32-row K/V LDS tiles aliased with the
//   16 KB accumulator park region -> 68 KB/block -> 2 blocks/CU (2 waves/SIMD).
//   Full 64x64 (d,m) plane per wave (per-lane 8x8, 64 acc VGPR): 4 ds_read_b128
//   per 64 FMAs, no barriers in the main loop (wave-private tiles, in-order DS).
//   Register double-buffer: next tile's global loads issued before compute.
// reduce: KVt = sum_sp KVp ; Ksum = sum_sp Ksump (grid 256)
// phase2: 256-row Q tiles, XOR-swizzled chunks (no pad) -> Qs 64 KB + KVs 16 KB
//   = exactly 80 KB -> 2 blocks/CU. Per-lane 8 rows x 8 m (16 b128 / 288 FMA).
//   Ksum read via uniform (scalar) loads from global.

#define SLEN 4096
#define LLEN 4096
#define NHTOT 64      // N*H
#define HD   512      // H*D row stride in elements
#define NSPLIT 8
#define EPSF 1e-6f

__device__ __forceinline__ float phi(float x) {
    return x > 0.0f ? x + 1.0f : __expf(x);
}

__device__ __forceinline__ void fma4(float4& a, float s, const float4& b) {
    a.x = fmaf(s, b.x, a.x);
    a.y = fmaf(s, b.y, a.y);
    a.z = fmaf(s, b.z, a.z);
    a.w = fmaf(s, b.w, a.w);
}

// ---------------- Phase 1: per-split KV partials ----------------
// grid (NSPLIT=8, 64), block 256 = 4 waves, 68 KB LDS -> 2 blocks/CU.
// Wave: 128 s-rows in 4 tiles of 32; private k/v tiles inside smem[w].
__global__ __launch_bounds__(256, 2)
void la_phase1(const float* __restrict__ Kg, const float* __restrict__ Vg,
               const float* __restrict__ maskg,
               float* __restrict__ KVp, float* __restrict__ Ksump) {
    __shared__ float smem[4][4096];  // per wave: [0..2047] K tile, [2048..4095] V tile; later 64x64 park
    __shared__ float ksb[16 * 64];   // ksum partials (4 KB) -> 68 KB total

    const int tid  = threadIdx.x;
    const int w    = tid >> 6;
    const int lane = tid & 63;
    const int nh   = blockIdx.y;
    const int n    = nh >> 3;
    const int h    = nh & 7;
    const int sp   = blockIdx.x;

    // staging role: 4 rows x 16 chunks per u-iter
    const int sr4 = lane >> 4;          // 0..3
    const int c4  = (lane & 15) * 4;    // float column
    // compute role: per-lane 8x8 tile of the full 64x64 plane
    const int d0  = (lane & 7) * 8;
    const int m0  = (lane >> 3) * 8;

    float* kw = smem[w];
    float* vw = smem[w] + 2048;

    const size_t base = (size_t)n * SLEN * HD + (size_t)h * 64;
    const float* mrow = maskg + (size_t)n * SLEN;
    const int wrow0 = sp * 512 + w * 128;   // wave's first s-row

    float4 acc[8][2];
    #pragma unroll
    for (int i = 0; i < 8; ++i) {
        acc[i][0] = make_float4(0.f, 0.f, 0.f, 0.f);
        acc[i][1] = make_float4(0.f, 0.f, 0.f, 0.f);
    }
    float4 ksp = make_float4(0.f, 0.f, 0.f, 0.f);

    // prologue: prefetch tile 0 into registers
    float4 pk[8], pv[8];
    float  pm[8];
    #pragma unroll
    for (int u = 0; u < 8; ++u) {
        const int s = wrow0 + sr4 + u * 4;
        const size_t g = base + (size_t)s * HD + c4;
        pk[u] = *(const float4*)(Kg + g);
        pv[u] = *(const float4*)(Vg + g);
        pm[u] = mrow[s];
    }

    #pragma unroll
    for (int t = 0; t < 4; ++t) {
        // ---- write staged regs -> LDS (phi+mask on K, ksum partial) ----
        #pragma unroll
        for (int u = 0; u < 8; ++u) {
            const int row = sr4 + u * 4;
            float4 kf = pk[u];
            const float mm = pm[u];
            kf.x = phi(kf.x) * mm;
            kf.y = phi(kf.y) * mm;
            kf.z = phi(kf.z) * mm;
            kf.w = phi(kf.w) * mm;
            ksp.x += kf.x; ksp.y += kf.y; ksp.z += kf.z; ksp.w += kf.w;
            *(float4*)&kw[row * 64 + c4] = kf;
            *(float4*)&vw[row * 64 + c4] = pv[u];
        }
        // ---- prefetch next tile (HBM latency hides under compute below) ----
        if (t < 3) {
            #pragma unroll
            for (int u = 0; u < 8; ++u) {
                const int s = wrow0 + (t + 1) * 32 + sr4 + u * 4;
                const size_t g = base + (size_t)s * HD + c4;
                pk[u] = *(const float4*)(Kg + g);
                pv[u] = *(const float4*)(Vg + g);
                pm[u] = mrow[s];
            }
        }
        // ---- full-plane outer product over 32 s-rows (wave-private, no barrier) ----
        #pragma unroll 4
        for (int s = 0; s < 32; ++s) {
            const float4 ka = *(const float4*)&kw[s * 64 + d0];
            const float4 kz = *(const float4*)&kw[s * 64 + d0 + 4];
            const float4 va = *(const float4*)&vw[s * 64 + m0];
            const float4 vz = *(const float4*)&vw[s * 64 + m0 + 4];
            fma4(acc[0][0], ka.x, va); fma4(acc[0][1], ka.x, vz);
            fma4(acc[1][0], ka.y, va); fma4(acc[1][1], ka.y, vz);
            fma4(acc[2][0], ka.z, va); fma4(acc[2][1], ka.z, vz);
            fma4(acc[3][0], ka.w, va); fma4(acc[3][1], ka.w, vz);
            fma4(acc[4][0], kz.x, va); fma4(acc[4][1], kz.x, vz);
            fma4(acc[5][0], kz.y, va); fma4(acc[5][1], kz.y, vz);
            fma4(acc[6][0], kz.z, va); fma4(acc[6][1], kz.z, vz);
            fma4(acc[7][0], kz.w, va); fma4(acc[7][1], kz.w, vz);
        }
    }

    // ---- ksum partials to LDS ----
    *(float4*)&ksb[(w * 4 + sr4) * 64 + c4] = ksp;

    // ---- park plane in smem[w] (16 KB, overwrites k/v tiles), block-reduce ----
    #pragma unroll
    for (int di = 0; di < 8; ++di) {
        *(float4*)&smem[w][(d0 + di) * 64 + m0]     = acc[di][0];
        *(float4*)&smem[w][(d0 + di) * 64 + m0 + 4] = acc[di][1];
    }
    __syncthreads();

    float* outp = KVp + ((size_t)sp * NHTOT + nh) * 4096;
    #pragma unroll
    for (int j = 0; j < 4; ++j) {
        const int f = (j * 256 + tid) * 4;
        float4 a  = *(const float4*)&smem[0][f];
        const float4 b1 = *(const float4*)&smem[1][f];
        const float4 b2 = *(const float4*)&smem[2][f];
        const float4 b3 = *(const float4*)&smem[3][f];
        a.x += b1.x + b2.x + b3.x;
        a.y += b1.y + b2.y + b3.y;
        a.z += b1.z + b2.z + b3.z;
        a.w += b1.w + b2.w + b3.w;
        *(float4*)&outp[f] = a;
    }
    if (tid < 64) {
        float ssum = 0.f;
        #pragma unroll
        for (int r = 0; r < 16; ++r) ssum += ksb[r * 64 + tid];
        Ksump[((size_t)sp * NHTOT + nh) * 64 + tid] = ssum;
    }
}

// ---------------- Reduce: sum the 8 split partials ----------------
// grid 256 (4 j-quarters per nh), block 256
__global__ __launch_bounds__(256)
void la_reduce(const float* __restrict__ KVp, const float* __restrict__ Ksump,
               float* __restrict__ KVt, float* __restrict__ Ksum) {
    const int nh  = blockIdx.x >> 2;
    const int j   = blockIdx.x & 3;
    const int tid = threadIdx.x;
    const int f = (j * 256 + tid) * 4;
    float4 a = make_float4(0.f, 0.f, 0.f, 0.f);
    #pragma unroll
    for (int s = 0; s < NSPLIT; ++s) {
        const float4 v = *(const float4*)&KVp[((size_t)s * NHTOT + nh) * 4096 + f];
        a.x += v.x; a.y += v.y; a.z += v.z; a.w += v.w;
    }
    *(float4*)&KVt[(size_t)nh * 4096 + f] = a;
    if (j == 0 && tid < 64) {
        float b = 0.f;
        #pragma unroll
        for (int s = 0; s < NSPLIT; ++s)
            b += Ksump[((size_t)s * NHTOT + nh) * 64 + tid];
        Ksum[nh * 64 + tid] = b;
    }
}

// ---------------- Phase 2: out = phi(Q) @ KVt, normalized ----------------
// grid (L/256, 64), block 256 = 4 waves, exactly 80 KB LDS -> 2 blocks/CU.
// Qs chunk-XOR-swizzled (no padding). Wave owns 64 rows; per-lane 8 rows x 8 m.
__global__ __launch_bounds__(256, 2)
void la_phase2(const float* __restrict__ Qg, const float* __restrict__ KVt,
               const float* __restrict__ Ksum, float* __restrict__ Og) {
    __shared__ float Qs[256 * 64];  // 64 KB, chunk c of row r stored at chunk (c ^ (r&7))
    __shared__ float KVs[64 * 64];  // 16 KB -> total exactly 80 KB

    const int tid = threadIdx.x;
    const int nh  = blockIdx.y;
    const int n   = nh >> 3;
    const int h   = nh & 7;
    const int lbase = blockIdx.x * 256;

    // ---- stage KVt (L2-hot, coalesced, linear layout) ----
    #pragma unroll
    for (int j = 0; j < 4; ++j) {
        const int f = (j * 256 + tid) * 4;
        *(float4*)&KVs[f] = *(const float4*)&KVt[(size_t)nh * 4096 + f];
    }

    // ---- stage phi(Q), 256 rows, XOR-swizzled chunk position ----
    const int sr = tid >> 4;           // 0..15
    const int cc = tid & 15;           // chunk index
    #pragma unroll
    for (int u = 0; u < 16; ++u) {
        const int row = u * 16 + sr;
        float4 q = *(const float4*)&Qg[((size_t)(n * LLEN + lbase + row) * 8 + h) * 64 + cc * 4];
        q.x = phi(q.x); q.y = phi(q.y); q.z = phi(q.z); q.w = phi(q.w);
        *(float4*)&Qs[row * 64 + (cc ^ (row & 7)) * 4] = q;
    }
    __syncthreads();

    const int w    = tid >> 6;        // wave -> 64-row band
    const int lane = tid & 63;
    const int ty   = lane >> 3;       // 0..7  (row group; row&7 == ty)
    const int tx   = lane & 7;        // 0..7
    const int m0   = tx * 8;
    const int rb   = w * 64 + ty;     // rows rb + 8*i, i<8

    float4 acc[8][2];
    float  den[8];
    #pragma unroll
    for (int i = 0; i < 8; ++i) {
        acc[i][0] = make_float4(0.f, 0.f, 0.f, 0.f);
        acc[i][1] = make_float4(0.f, 0.f, 0.f, 0.f);
        den[i] = 0.f;
    }

    const float* ksrow = Ksum + nh * 64;   // uniform address -> scalar loads

    for (int d4 = 0; d4 < 16; ++d4) {
        const float4 ks = *(const float4*)&ksrow[d4 * 4];
        float4 q4[8];
        #pragma unroll
        for (int i = 0; i < 8; ++i)
            q4[i] = *(const float4*)&Qs[(rb + 8 * i) * 64 + ((d4 ^ ty) * 4)];
        #pragma unroll
        for (int i = 0; i < 8; ++i) {
            den[i] = fmaf(q4[i].x, ks.x, den[i]);
            den[i] = fmaf(q4[i].y, ks.y, den[i]);
            den[i] = fmaf(q4[i].z, ks.z, den[i]);
            den[i] = fmaf(q4[i].w, ks.w, den[i]);
        }
        #pragma unroll
        for (int dk = 0; dk < 4; ++dk) {
            const float4 kva = *(const float4*)&KVs[(d4 * 4 + dk) * 64 + m0];
            const float4 kvz = *(const float4*)&KVs[(d4 * 4 + dk) * 64 + m0 + 4];
            #pragma unroll
            for (int i = 0; i < 8; ++i) {
                const float qv = (&q4[i].x)[dk];
                fma4(acc[i][0], qv, kva);
                fma4(acc[i][1], qv, kvz);
            }
        }
    }

    // ---- normalize + store (2 float4 = 32 B contiguous per row per lane) ----
    #pragma unroll
    for (int i = 0; i < 8; ++i) {
        const int l = lbase + rb + 8 * i;
        const float z = 1.0f / (den[i] + EPSF);
        float4 o0 = acc[i][0], o1 = acc[i][1];
        o0.x *= z; o0.y *= z; o0.z *= z; o0.w *= z;
        o1.x *= z; o1.y *= z; o1.z *= z; o1.w *= z;
        float* op = &Og[((size_t)(n * LLEN + l) * 8 + h) * 64 + m0];
        *(float4*)op       = o0;
        *(float4*)(op + 4) = o1;
    }
}

extern "C" void kernel_launch(void* const* d_in, const int* in_sizes, int n_in,
                              void* d_out, int out_size, void* d_ws, size_t ws_size,
                              hipStream_t stream) {
    const float* Q    = (const float*)d_in[0];
    const float* K    = (const float*)d_in[1];
    const float* V    = (const float*)d_in[2];
    const float* mask = (const float*)d_in[3];
    float* out = (float*)d_out;

    float* KVp   = (float*)d_ws;                                  // [8][64][4096] = 8 MB
    float* Ksump = KVp + (size_t)NSPLIT * NHTOT * 4096;           // [8][64][64]
    float* KVt   = Ksump + (size_t)NSPLIT * NHTOT * 64;           // [64][4096]
    float* Ksum  = KVt + (size_t)NHTOT * 4096;                    // [64][64]
    // every ws element read is written first (no memset needed)

    dim3 g1(NSPLIT, NHTOT);
    la_phase1<<<g1, 256, 0, stream>>>(K, V, mask, KVp, Ksump);

    la_reduce<<<256, 256, 0, stream>>>(KVp, Ksump, KVt, Ksum);

    dim3 g2(LLEN / 256, NHTOT);
    la_phase2<<<g2, 256, 0, stream>>>(Q, KVt, Ksum, out);
}

// Round 3
// 249.732 us; speedup vs baseline: 1.0987x; 1.0494x over previous
//
#include <hip/hip_runtime.h>

// LinearAttention: N=8, L=S=4096, H=8, D=M=64, fp32.
// phase1 (8 s-splits): UNCHANGED from prior round (fp32 VALU outer-product,
//   per-wave-private LDS tiles, 2 blocks/CU, ~70us, verified).
// reduce: sums 8 split partials; emits KV^T as bf16 hi/lo pair ([m][d] layout,
//   i.e. B^T layout for MFMA) + fp32 Ksum. LDS slab transpose, coalesced loads.
// phase2 (MFMA): out[l][m] = phi(Q)[l,:] . KV[:,m] / (phi(Q)[l,:] . Ksum + eps)
//   via mfma_f32_16x16x32_bf16 with hi/lo split (qh*kh + qh*kl + ql*kh).
//   A-frags (Q rows, d-contiguous) loaded straight from global; B-frags from
//   bf16 KV^T (L2-hot); denominator in exact fp32 VALU. No LDS, no barriers.

#define SLEN 4096
#define LLEN 4096
#define NHTOT 64      // N*H
#define HD   512      // H*D row stride in elements
#define NSPLIT 8
#define EPSF 1e-6f

typedef short s16x8 __attribute__((ext_vector_type(8)));
typedef float f32x4 __attribute__((ext_vector_type(4)));

__device__ __forceinline__ float phi(float x) {
    return x > 0.0f ? x + 1.0f : __expf(x);
}

__device__ __forceinline__ void fma4(float4& a, float s, const float4& b) {
    a.x = fmaf(s, b.x, a.x);
    a.y = fmaf(s, b.y, a.y);
    a.z = fmaf(s, b.z, a.z);
    a.w = fmaf(s, b.w, a.w);
}

// truncation bf16 split: x ~= hi + lo to ~16 mantissa bits (x-hf exact by Sterbenz)
__device__ __forceinline__ void bsplit(float x, short& hi, short& lo) {
    const unsigned bx = __float_as_uint(x);
    hi = (short)(bx >> 16);
    const float hf = __uint_as_float(bx & 0xFFFF0000u);
    lo = (short)(__float_as_uint(x - hf) >> 16);
}

// ---------------- Phase 1: per-split KV partials (UNCHANGED) ----------------
__global__ __launch_bounds__(256, 2)
void la_phase1(const float* __restrict__ Kg, const float* __restrict__ Vg,
               const float* __restrict__ maskg,
               float* __restrict__ KVp, float* __restrict__ Ksump) {
    __shared__ float smem[4][4096];
    __shared__ float ksb[16 * 64];

    const int tid  = threadIdx.x;
    const int w    = tid >> 6;
    const int lane = tid & 63;
    const int nh   = blockIdx.y;
    const int n    = nh >> 3;
    const int h    = nh & 7;
    const int sp   = blockIdx.x;

    const int sr4 = lane >> 4;
    const int c4  = (lane & 15) * 4;
    const int d0  = (lane & 7) * 8;
    const int m0  = (lane >> 3) * 8;

    float* kw = smem[w];
    float* vw = smem[w] + 2048;

    const size_t base = (size_t)n * SLEN * HD + (size_t)h * 64;
    const float* mrow = maskg + (size_t)n * SLEN;
    const int wrow0 = sp * 512 + w * 128;

    float4 acc[8][2];
    #pragma unroll
    for (int i = 0; i < 8; ++i) {
        acc[i][0] = make_float4(0.f, 0.f, 0.f, 0.f);
        acc[i][1] = make_float4(0.f, 0.f, 0.f, 0.f);
    }
    float4 ksp = make_float4(0.f, 0.f, 0.f, 0.f);

    float4 pk[8], pv[8];
    float  pm[8];
    #pragma unroll
    for (int u = 0; u < 8; ++u) {
        const int s = wrow0 + sr4 + u * 4;
        const size_t g = base + (size_t)s * HD + c4;
        pk[u] = *(const float4*)(Kg + g);
        pv[u] = *(const float4*)(Vg + g);
        pm[u] = mrow[s];
    }

    #pragma unroll
    for (int t = 0; t < 4; ++t) {
        #pragma unroll
        for (int u = 0; u < 8; ++u) {
            const int row = sr4 + u * 4;
            float4 kf = pk[u];
            const float mm = pm[u];
            kf.x = phi(kf.x) * mm;
            kf.y = phi(kf.y) * mm;
            kf.z = phi(kf.z) * mm;
            kf.w = phi(kf.w) * mm;
            ksp.x += kf.x; ksp.y += kf.y; ksp.z += kf.z; ksp.w += kf.w;
            *(float4*)&kw[row * 64 + c4] = kf;
            *(float4*)&vw[row * 64 + c4] = pv[u];
        }
        if (t < 3) {
            #pragma unroll
            for (int u = 0; u < 8; ++u) {
                const int s = wrow0 + (t + 1) * 32 + sr4 + u * 4;
                const size_t g = base + (size_t)s * HD + c4;
                pk[u] = *(const float4*)(Kg + g);
                pv[u] = *(const float4*)(Vg + g);
                pm[u] = mrow[s];
            }
        }
        #pragma unroll 4
        for (int s = 0; s < 32; ++s) {
            const float4 ka = *(const float4*)&kw[s * 64 + d0];
            const float4 kz = *(const float4*)&kw[s * 64 + d0 + 4];
            const float4 va = *(const float4*)&vw[s * 64 + m0];
            const float4 vz = *(const float4*)&vw[s * 64 + m0 + 4];
            fma4(acc[0][0], ka.x, va); fma4(acc[0][1], ka.x, vz);
            fma4(acc[1][0], ka.y, va); fma4(acc[1][1], ka.y, vz);
            fma4(acc[2][0], ka.z, va); fma4(acc[2][1], ka.z, vz);
            fma4(acc[3][0], ka.w, va); fma4(acc[3][1], ka.w, vz);
            fma4(acc[4][0], kz.x, va); fma4(acc[4][1], kz.x, vz);
            fma4(acc[5][0], kz.y, va); fma4(acc[5][1], kz.y, vz);
            fma4(acc[6][0], kz.z, va); fma4(acc[6][1], kz.z, vz);
            fma4(acc[7][0], kz.w, va); fma4(acc[7][1], kz.w, vz);
        }
    }

    *(float4*)&ksb[(w * 4 + sr4) * 64 + c4] = ksp;

    #pragma unroll
    for (int di = 0; di < 8; ++di) {
        *(float4*)&smem[w][(d0 + di) * 64 + m0]     = acc[di][0];
        *(float4*)&smem[w][(d0 + di) * 64 + m0 + 4] = acc[di][1];
    }
    __syncthreads();

    float* outp = KVp + ((size_t)sp * NHTOT + nh) * 4096;
    #pragma unroll
    for (int j = 0; j < 4; ++j) {
        const int f = (j * 256 + tid) * 4;
        float4 a  = *(const float4*)&smem[0][f];
        const float4 b1 = *(const float4*)&smem[1][f];
        const float4 b2 = *(const float4*)&smem[2][f];
        const float4 b3 = *(const float4*)&smem[3][f];
        a.x += b1.x + b2.x + b3.x;
        a.y += b1.y + b2.y + b3.y;
        a.z += b1.z + b2.z + b3.z;
        a.w += b1.w + b2.w + b3.w;
        *(float4*)&outp[f] = a;
    }
    if (tid < 64) {
        float ssum = 0.f;
        #pragma unroll
        for (int r = 0; r < 16; ++r) ssum += ksb[r * 64 + tid];
        Ksump[((size_t)sp * NHTOT + nh) * 64 + tid] = ssum;
    }
}

// ---------------- Reduce + transpose + bf16 split ----------------
// grid (4, 64): block handles m-range [bx*16, bx*16+16) of one nh.
// Coalesced slab loads (KVp is [d*64+m]); LDS transpose; emit KVT[m][d] hi/lo.
__global__ __launch_bounds__(256)
void la_reduce(const float* __restrict__ KVp, const float* __restrict__ Ksump,
               short* __restrict__ KVThi, short* __restrict__ KVTlo,
               float* __restrict__ Ksum) {
    __shared__ float ld[64 * 20];   // [64 d][16 m], stride 20 (16B-aligned rows)

    const int nh  = blockIdx.y;
    const int mb  = blockIdx.x * 16;
    const int tid = threadIdx.x;

    // load role: d = tid>>2, 16B chunk (tid&3) of the 64B m-slab row
    const int d    = tid >> 2;
    const int moff = (tid & 3) * 4;
    float4 a = make_float4(0.f, 0.f, 0.f, 0.f);
    #pragma unroll
    for (int s = 0; s < NSPLIT; ++s) {
        const float4 v = *(const float4*)&KVp[((size_t)s * NHTOT + nh) * 4096 + d * 64 + mb + moff];
        a.x += v.x; a.y += v.y; a.z += v.z; a.w += v.w;
    }
    *(float4*)&ld[d * 20 + moff] = a;
    __syncthreads();

    // store role: m-row (tid>>4), 4 consecutive d (tid&15)*4
    const int mloc = tid >> 4;
    const int d0   = (tid & 15) * 4;
    short hi4[4], lo4[4];
    #pragma unroll
    for (int i = 0; i < 4; ++i)
        bsplit(ld[(d0 + i) * 20 + mloc], hi4[i], lo4[i]);
    const size_t o = (size_t)nh * 4096 + (mb + mloc) * 64 + d0;
    *(short4*)&KVThi[o] = *(short4*)hi4;
    *(short4*)&KVTlo[o] = *(short4*)lo4;

    if (blockIdx.x == 0 && tid < 64) {
        float b = 0.f;
        #pragma unroll
        for (int s = 0; s < NSPLIT; ++s)
            b += Ksump[((size_t)s * NHTOT + nh) * 64 + tid];
        Ksum[nh * 64 + tid] = b;
    }
}

// ---------------- Phase 2: MFMA out = phi(Q) @ KV, normalized ----------------
// grid (L/128, 64), block 256 = 4 waves. Wave: 32 l-rows (2 M-tiles) x 64 m
// (4 N-tiles), K=64 d in 2 steps of 32. 48 mfma_f32_16x16x32_bf16 per wave.
// No LDS, no barriers. Denominator in exact fp32.
__global__ __launch_bounds__(256)
void la_phase2(const float* __restrict__ Qg,
               const short* __restrict__ KVThi, const short* __restrict__ KVTlo,
               const float* __restrict__ Ksum, float* __restrict__ Og) {
    const int tid  = threadIdx.x;
    const int w    = tid >> 6;
    const int lane = tid & 63;
    const int nh   = blockIdx.y;
    const int n    = nh >> 3;
    const int h    = nh & 7;
    const int l0   = blockIdx.x * 128 + w * 32;

    const int r  = lane & 15;      // A: M-row within tile / B: N-col within tile
    const int g4 = lane >> 4;      // k-group (8 consecutive k each)

    const short* bhp = KVThi + (size_t)nh * 4096;   // [m][d] bf16
    const short* blp = KVTlo + (size_t)nh * 4096;
    const float* ksp = Ksum + nh * 64;

    f32x4 acc[2][4];
    #pragma unroll
    for (int t = 0; t < 2; ++t)
        #pragma unroll
        for (int u = 0; u < 4; ++u)
            acc[t][u] = (f32x4){0.f, 0.f, 0.f, 0.f};
    float den[2] = {0.f, 0.f};

    #pragma unroll
    for (int g = 0; g < 2; ++g) {
        const int db = g * 32 + g4 * 8;   // this lane's 8 k (d) values

        s16x8 Bh[4], Bl[4];
        #pragma unroll
        for (int u = 0; u < 4; ++u) {
            Bh[u] = *(const s16x8*)&bhp[(u * 16 + r) * 64 + db];
            Bl[u] = *(const s16x8*)&blp[(u * 16 + r) * 64 + db];
        }
        const float4 k0 = *(const float4*)&ksp[db];
        const float4 k1 = *(const float4*)&ksp[db + 4];

        #pragma unroll
        for (int t = 0; t < 2; ++t) {
            const float* qrow = Qg + ((size_t)(n * LLEN + l0 + t * 16 + r) * 8 + h) * 64 + db;
            float4 q0 = *(const float4*)qrow;
            float4 q1 = *(const float4*)(qrow + 4);
            q0.x = phi(q0.x); q0.y = phi(q0.y); q0.z = phi(q0.z); q0.w = phi(q0.w);
            q1.x = phi(q1.x); q1.y = phi(q1.y); q1.z = phi(q1.z); q1.w = phi(q1.w);

            float dn = den[t];
            dn = fmaf(q0.x, k0.x, dn); dn = fmaf(q0.y, k0.y, dn);
            dn = fmaf(q0.z, k0.z, dn); dn = fmaf(q0.w, k0.w, dn);
            dn = fmaf(q1.x, k1.x, dn); dn = fmaf(q1.y, k1.y, dn);
            dn = fmaf(q1.z, k1.z, dn); dn = fmaf(q1.w, k1.w, dn);
            den[t] = dn;

            s16x8 Ah, Al;
            {
                short hh, ll;
                bsplit(q0.x, hh, ll); Ah[0] = hh; Al[0] = ll;
                bsplit(q0.y, hh, ll); Ah[1] = hh; Al[1] = ll;
                bsplit(q0.z, hh, ll); Ah[2] = hh; Al[2] = ll;
                bsplit(q0.w, hh, ll); Ah[3] = hh; Al[3] = ll;
                bsplit(q1.x, hh, ll); Ah[4] = hh; Al[4] = ll;
                bsplit(q1.y, hh, ll); Ah[5] = hh; Al[5] = ll;
                bsplit(q1.z, hh, ll); Ah[6] = hh; Al[6] = ll;
                bsplit(q1.w, hh, ll); Ah[7] = hh; Al[7] = ll;
            }
            #pragma unroll
            for (int u = 0; u < 4; ++u) {
                acc[t][u] = __builtin_amdgcn_mfma_f32_16x16x32_bf16(Ah, Bh[u], acc[t][u], 0, 0, 0);
                acc[t][u] = __builtin_amdgcn_mfma_f32_16x16x32_bf16(Ah, Bl[u], acc[t][u], 0, 0, 0);
                acc[t][u] = __builtin_amdgcn_mfma_f32_16x16x32_bf16(Al, Bh[u], acc[t][u], 0, 0, 0);
            }
        }
    }

    // den: sum the 4 k-group partials -> every lane holds den of its row r
    #pragma unroll
    for (int t = 0; t < 2; ++t) {
        den[t] += __shfl_xor(den[t], 16, 64);
        den[t] += __shfl_xor(den[t], 32, 64);
    }

    // epilogue: D layout col = lane&15 (m in tile), row = g4*4 + reg
    #pragma unroll
    for (int t = 0; t < 2; ++t) {
        #pragma unroll
        for (int k = 0; k < 4; ++k) {
            const int ro = g4 * 4 + k;                       // row within tile
            const float dk = __shfl(den[t], ro, 64);         // den of that row
            const float z  = 1.0f / (dk + EPSF);
            const int l = l0 + t * 16 + ro;
            float* op = &Og[((size_t)(n * LLEN + l) * 8 + h) * 64 + r];
            #pragma unroll
            for (int u = 0; u < 4; ++u)
                op[u * 16] = acc[t][u][k] * z;
        }
    }
}

extern "C" void kernel_launch(void* const* d_in, const int* in_sizes, int n_in,
                              void* d_out, int out_size, void* d_ws, size_t ws_size,
                              hipStream_t stream) {
    const float* Q    = (const float*)d_in[0];
    const float* K    = (const float*)d_in[1];
    const float* V    = (const float*)d_in[2];
    const float* mask = (const float*)d_in[3];
    float* out = (float*)d_out;

    float* KVp   = (float*)d_ws;                              // [8][64][4096] f32 = 8 MB
    float* Ksump = KVp + (size_t)NSPLIT * NHTOT * 4096;       // [8][64][64]
    float* Ksum  = Ksump + (size_t)NSPLIT * NHTOT * 64;       // [64][64] f32
    short* KVThi = (short*)(Ksum + NHTOT * 64);               // [64][64m][64d] bf16
    short* KVTlo = KVThi + (size_t)NHTOT * 4096;
    // every ws element read is written first (no memset needed)

    dim3 g1(NSPLIT, NHTOT);
    la_phase1<<<g1, 256, 0, stream>>>(K, V, mask, KVp, Ksump);

    dim3 gr(4, NHTOT);
    la_reduce<<<gr, 256, 0, stream>>>(KVp, Ksump, KVThi, KVTlo, Ksum);

    dim3 g2(LLEN / 128, NHTOT);
    la_phase2<<<g2, 256, 0, stream>>>(Q, KVThi, KVTlo, Ksum, out);
}

// Round 4
// 239.336 us; speedup vs baseline: 1.1464x; 1.0434x over previous
//
#include <hip/hip_runtime.h>

// LinearAttention: N=8, L=S=4096, H=8, D=M=64, fp32.
// phase1 (8 s-splits, MFMA): per-wave-private LDS tiles, K/V transposed to
//   [d][32 s] / [m][32 s] bf16 hi/lo (chunk-XOR swizzle, packed b64 writes).
//   48 mfma_f32_16x16x32_bf16 per 32-s k-step (hi*hi + hi*lo + lo*hi).
//   No main-loop barriers (wave-private, in-order DS); register prefetch of
//   next tile; fp32 64x64 park aliases staging; block-reduce at end.
//   Ksum accumulated in exact fp32 VALU. 68 KB LDS -> 2 blocks/CU.
// reduce: sums 8 split partials; emits KV^T bf16 hi/lo ([m][d]) + fp32 Ksum.
// phase2 (MFMA, unchanged from round 3 - verified): Q straight from global,
//   bf16 hi/lo split, no LDS, no barriers; denominator exact fp32.

#define SLEN 4096
#define LLEN 4096
#define NHTOT 64      // N*H
#define HD   512      // H*D row stride in elements
#define NSPLIT 8
#define EPSF 1e-6f

typedef short s16x8 __attribute__((ext_vector_type(8)));
typedef float f32x4 __attribute__((ext_vector_type(4)));

__device__ __forceinline__ float phi(float x) {
    return x > 0.0f ? x + 1.0f : __expf(x);
}

// pack bf16(hi) of two floats into one u32 (a -> low half = lower s index)
__device__ __forceinline__ unsigned pack_hi2(float a, float b) {
    return (__float_as_uint(a) >> 16) | (__float_as_uint(b) & 0xFFFF0000u);
}
// residual after bf16 truncation (exact)
__device__ __forceinline__ float bres(float x) {
    return x - __uint_as_float(__float_as_uint(x) & 0xFFFF0000u);
}
// scalar split for reduce kernel
__device__ __forceinline__ void bsplit(float x, short& hi, short& lo) {
    const unsigned bx = __float_as_uint(x);
    hi = (short)(bx >> 16);
    const float hf = __uint_as_float(bx & 0xFFFF0000u);
    lo = (short)(__float_as_uint(x - hf) >> 16);
}

// ---------------- Phase 1: per-split KV partials via MFMA ----------------
// grid (NSPLIT=8, 64), block 256 = 4 waves, 68 KB LDS -> 2 blocks/CU.
// Wave: 128 s-rows in 4 k-steps of 32. Transposed bf16 tiles in private LDS:
//   element (d, s) at byte d*64 + ((s>>3) ^ ((d>>2)&3))*16 + (s&7)*2.
__global__ __launch_bounds__(256, 2)
void la_phase1(const float* __restrict__ Kg, const float* __restrict__ Vg,
               const float* __restrict__ maskg,
               float* __restrict__ KVp, float* __restrict__ Ksump) {
    __shared__ float smem[4][4096];  // per wave 16 KB: KThi|KTlo|VThi|VTlo (4 KB each); later fp32 park
    __shared__ float ksb[16 * 64];   // ksum partials (4 KB) -> 68 KB total

    const int tid  = threadIdx.x;
    const int w    = tid >> 6;
    const int lane = tid & 63;
    const int nh   = blockIdx.y;
    const int n    = nh >> 3;
    const int h    = nh & 7;
    const int sp   = blockIdx.x;

    const int r  = lane & 15;     // staging: d-chunk id | mfma: tile row (A) / col (B) / D-col
    const int a  = lane >> 4;     // staging: s row-quad | mfma: k-group, D row-group
    const int c4 = r * 4;         // first d of this lane's staging chunk

    char* const wbase = (char*)&smem[w][0];
    char* const kthi = wbase;             // 4 KB each
    char* const ktlo = wbase + 4096;
    char* const vthi = wbase + 8192;
    char* const vtlo = wbase + 12288;

    const size_t base = (size_t)n * SLEN * HD + (size_t)h * 64;
    const float* mrow = maskg + (size_t)n * SLEN;
    const int wrow0 = sp * 512 + w * 128;   // wave's first s-row

    // write offset within a d-row for this lane's b64 (s0 = u*16 + a*4):
    //   chunk = (s0>>3) ^ (r&3) [key (d>>2)&3 == r&3 for all 4 of this lane's d]
    const int woff0 = ((((a >> 1) ^ (r & 3)) << 4) | ((a & 1) << 3));
    const int rkey  = (r >> 2) & 3;   // read-side swizzle key for row d=dt*16+r

    f32x4 acc[4][4];   // [dt][mt]
    #pragma unroll
    for (int i = 0; i < 4; ++i)
        #pragma unroll
        for (int j = 0; j < 4; ++j)
            acc[i][j] = (f32x4){0.f, 0.f, 0.f, 0.f};
    float4 ksp = make_float4(0.f, 0.f, 0.f, 0.f);

    // prologue: prefetch k-step 0 (lane: rows u*16 + a*4 + j, cols c4..c4+3)
    float4 pk[2][4], pv[2][4];
    float  pm[2][4];
    #pragma unroll
    for (int u = 0; u < 2; ++u)
        #pragma unroll
        for (int j = 0; j < 4; ++j) {
            const int s = wrow0 + u * 16 + a * 4 + j;
            const size_t g = base + (size_t)s * HD + c4;
            pk[u][j] = *(const float4*)(Kg + g);
            pv[u][j] = *(const float4*)(Vg + g);
            pm[u][j] = mrow[s];
        }

    #pragma unroll
    for (int t = 0; t < 4; ++t) {
        // ---- phi/mask/ksum + bf16 split + transposed LDS write ----
        #pragma unroll
        for (int u = 0; u < 2; ++u) {
            float4 kf[4];
            #pragma unroll
            for (int j = 0; j < 4; ++j) {
                float4 kq = pk[u][j];
                const float mm = pm[u][j];
                kq.x = phi(kq.x) * mm; kq.y = phi(kq.y) * mm;
                kq.z = phi(kq.z) * mm; kq.w = phi(kq.w) * mm;
                kf[j] = kq;
                ksp.x += kq.x; ksp.y += kq.y; ksp.z += kq.z; ksp.w += kq.w;
            }
            const int wo = woff0 ^ (u << 5);
            #pragma unroll
            for (int i = 0; i < 4; ++i) {
                const int doff = r * 256 + i * 64 + wo;
                const float k0 = (&kf[0].x)[i], k1 = (&kf[1].x)[i];
                const float k2 = (&kf[2].x)[i], k3 = (&kf[3].x)[i];
                *(uint2*)(kthi + doff) = make_uint2(pack_hi2(k0, k1), pack_hi2(k2, k3));
                *(uint2*)(ktlo + doff) = make_uint2(pack_hi2(bres(k0), bres(k1)),
                                                   pack_hi2(bres(k2), bres(k3)));
                const float v0 = (&pv[u][0].x)[i], v1 = (&pv[u][1].x)[i];
                const float v2 = (&pv[u][2].x)[i], v3 = (&pv[u][3].x)[i];
                *(uint2*)(vthi + doff) = make_uint2(pack_hi2(v0, v1), pack_hi2(v2, v3));
                *(uint2*)(vtlo + doff) = make_uint2(pack_hi2(bres(v0), bres(v1)),
                                                   pack_hi2(bres(v2), bres(v3)));
            }
        }
        // ---- prefetch next k-step (flies under mfma below) ----
        if (t < 3) {
            #pragma unroll
            for (int u = 0; u < 2; ++u)
                #pragma unroll
                for (int j = 0; j < 4; ++j) {
                    const int s = wrow0 + (t + 1) * 32 + u * 16 + a * 4 + j;
                    const size_t g = base + (size_t)s * HD + c4;
                    pk[u][j] = *(const float4*)(Kg + g);
                    pv[u][j] = *(const float4*)(Vg + g);
                    pm[u][j] = mrow[s];
                }
        }
        // ---- frag reads + 48 MFMA (in-wave DS order: writes above are seen) ----
        s16x8 Ah[4], Al[4];
        const int cho = (a ^ rkey) << 4;
        #pragma unroll
        for (int dt = 0; dt < 4; ++dt) {
            const int off = dt * 1024 + r * 64 + cho;
            Ah[dt] = *(const s16x8*)(kthi + off);
            Al[dt] = *(const s16x8*)(ktlo + off);
        }
        #pragma unroll
        for (int mt = 0; mt < 4; ++mt) {
            const int off = mt * 1024 + r * 64 + cho;
            const s16x8 Bh = *(const s16x8*)(vthi + off);
            const s16x8 Bl = *(const s16x8*)(vtlo + off);
            #pragma unroll
            for (int dt = 0; dt < 4; ++dt) {
                acc[dt][mt] = __builtin_amdgcn_mfma_f32_16x16x32_bf16(Ah[dt], Bh, acc[dt][mt], 0, 0, 0);
                acc[dt][mt] = __builtin_amdgcn_mfma_f32_16x16x32_bf16(Ah[dt], Bl, acc[dt][mt], 0, 0, 0);
                acc[dt][mt] = __builtin_amdgcn_mfma_f32_16x16x32_bf16(Al[dt], Bh, acc[dt][mt], 0, 0, 0);
            }
        }
    }

    // ---- ksum partials to LDS ----
    *(float4*)&ksb[(w * 4 + a) * 64 + c4] = ksp;

    // ---- park plane [d][m] fp32 in wave's own region (aliases staging) ----
    // D layout: col = lane&15 = r (m in tile), row = a*4 + p (d in tile).
    float* pw = &smem[w][0];
    #pragma unroll
    for (int dt = 0; dt < 4; ++dt)
        #pragma unroll
        for (int mt = 0; mt < 4; ++mt)
            #pragma unroll
            for (int p = 0; p < 4; ++p)
                pw[(dt * 16 + a * 4 + p) * 64 + mt * 16 + r] = acc[dt][mt][p];
    __syncthreads();

    float* outp = KVp + ((size_t)sp * NHTOT + nh) * 4096;
    #pragma unroll
    for (int j = 0; j < 4; ++j) {
        const int f = (j * 256 + tid) * 4;
        float4 s0  = *(const float4*)&smem[0][f];
        const float4 b1 = *(const float4*)&smem[1][f];
        const float4 b2 = *(const float4*)&smem[2][f];
        const float4 b3 = *(const float4*)&smem[3][f];
        s0.x += b1.x + b2.x + b3.x;
        s0.y += b1.y + b2.y + b3.y;
        s0.z += b1.z + b2.z + b3.z;
        s0.w += b1.w + b2.w + b3.w;
        *(float4*)&outp[f] = s0;
    }
    if (tid < 64) {
        float ssum = 0.f;
        #pragma unroll
        for (int rr = 0; rr < 16; ++rr) ssum += ksb[rr * 64 + tid];
        Ksump[((size_t)sp * NHTOT + nh) * 64 + tid] = ssum;
    }
}

// ---------------- Reduce + transpose + bf16 split ----------------
// grid (4, 64): block handles m-range [bx*16, bx*16+16) of one nh.
__global__ __launch_bounds__(256)
void la_reduce(const float* __restrict__ KVp, const float* __restrict__ Ksump,
               short* __restrict__ KVThi, short* __restrict__ KVTlo,
               float* __restrict__ Ksum) {
    __shared__ float ld[64 * 20];   // [64 d][16 m], stride 20

    const int nh  = blockIdx.y;
    const int mb  = blockIdx.x * 16;
    const int tid = threadIdx.x;

    const int d    = tid >> 2;
    const int moff = (tid & 3) * 4;
    float4 a = make_float4(0.f, 0.f, 0.f, 0.f);
    #pragma unroll
    for (int s = 0; s < NSPLIT; ++s) {
        const float4 v = *(const float4*)&KVp[((size_t)s * NHTOT + nh) * 4096 + d * 64 + mb + moff];
        a.x += v.x; a.y += v.y; a.z += v.z; a.w += v.w;
    }
    *(float4*)&ld[d * 20 + moff] = a;
    __syncthreads();

    const int mloc = tid >> 4;
    const int d0   = (tid & 15) * 4;
    short hi4[4], lo4[4];
    #pragma unroll
    for (int i = 0; i < 4; ++i)
        bsplit(ld[(d0 + i) * 20 + mloc], hi4[i], lo4[i]);
    const size_t o = (size_t)nh * 4096 + (mb + mloc) * 64 + d0;
    *(short4*)&KVThi[o] = *(short4*)hi4;
    *(short4*)&KVTlo[o] = *(short4*)lo4;

    if (blockIdx.x == 0 && tid < 64) {
        float b = 0.f;
        #pragma unroll
        for (int s = 0; s < NSPLIT; ++s)
            b += Ksump[((size_t)s * NHTOT + nh) * 64 + tid];
        Ksum[nh * 64 + tid] = b;
    }
}

// ---------------- Phase 2: MFMA out = phi(Q) @ KV, normalized ----------------
// (unchanged from round 3 - verified)
__global__ __launch_bounds__(256)
void la_phase2(const float* __restrict__ Qg,
               const short* __restrict__ KVThi, const short* __restrict__ KVTlo,
               const float* __restrict__ Ksum, float* __restrict__ Og) {
    const int tid  = threadIdx.x;
    const int w    = tid >> 6;
    const int lane = tid & 63;
    const int nh   = blockIdx.y;
    const int n    = nh >> 3;
    const int h    = nh & 7;
    const int l0   = blockIdx.x * 128 + w * 32;

    const int r  = lane & 15;
    const int g4 = lane >> 4;

    const short* bhp = KVThi + (size_t)nh * 4096;
    const short* blp = KVTlo + (size_t)nh * 4096;
    const float* ksp = Ksum + nh * 64;

    f32x4 acc[2][4];
    #pragma unroll
    for (int t = 0; t < 2; ++t)
        #pragma unroll
        for (int u = 0; u < 4; ++u)
            acc[t][u] = (f32x4){0.f, 0.f, 0.f, 0.f};
    float den[2] = {0.f, 0.f};

    #pragma unroll
    for (int g = 0; g < 2; ++g) {
        const int db = g * 32 + g4 * 8;

        s16x8 Bh[4], Bl[4];
        #pragma unroll
        for (int u = 0; u < 4; ++u) {
            Bh[u] = *(const s16x8*)&bhp[(u * 16 + r) * 64 + db];
            Bl[u] = *(const s16x8*)&blp[(u * 16 + r) * 64 + db];
        }
        const float4 k0 = *(const float4*)&ksp[db];
        const float4 k1 = *(const float4*)&ksp[db + 4];

        #pragma unroll
        for (int t = 0; t < 2; ++t) {
            const float* qrow = Qg + ((size_t)(n * LLEN + l0 + t * 16 + r) * 8 + h) * 64 + db;
            float4 q0 = *(const float4*)qrow;
            float4 q1 = *(const float4*)(qrow + 4);
            q0.x = phi(q0.x); q0.y = phi(q0.y); q0.z = phi(q0.z); q0.w = phi(q0.w);
            q1.x = phi(q1.x); q1.y = phi(q1.y); q1.z = phi(q1.z); q1.w = phi(q1.w);

            float dn = den[t];
            dn = fmaf(q0.x, k0.x, dn); dn = fmaf(q0.y, k0.y, dn);
            dn = fmaf(q0.z, k0.z, dn); dn = fmaf(q0.w, k0.w, dn);
            dn = fmaf(q1.x, k1.x, dn); dn = fmaf(q1.y, k1.y, dn);
            dn = fmaf(q1.z, k1.z, dn); dn = fmaf(q1.w, k1.w, dn);
            den[t] = dn;

            s16x8 Ah, Al;
            {
                short hh, ll;
                bsplit(q0.x, hh, ll); Ah[0] = hh; Al[0] = ll;
                bsplit(q0.y, hh, ll); Ah[1] = hh; Al[1] = ll;
                bsplit(q0.z, hh, ll); Ah[2] = hh; Al[2] = ll;
                bsplit(q0.w, hh, ll); Ah[3] = hh; Al[3] = ll;
                bsplit(q1.x, hh, ll); Ah[4] = hh; Al[4] = ll;
                bsplit(q1.y, hh, ll); Ah[5] = hh; Al[5] = ll;
                bsplit(q1.z, hh, ll); Ah[6] = hh; Al[6] = ll;
                bsplit(q1.w, hh, ll); Ah[7] = hh; Al[7] = ll;
            }
            #pragma unroll
            for (int u = 0; u < 4; ++u) {
                acc[t][u] = __builtin_amdgcn_mfma_f32_16x16x32_bf16(Ah, Bh[u], acc[t][u], 0, 0, 0);
                acc[t][u] = __builtin_amdgcn_mfma_f32_16x16x32_bf16(Ah, Bl[u], acc[t][u], 0, 0, 0);
                acc[t][u] = __builtin_amdgcn_mfma_f32_16x16x32_bf16(Al, Bh[u], acc[t][u], 0, 0, 0);
            }
        }
    }

    #pragma unroll
    for (int t = 0; t < 2; ++t) {
        den[t] += __shfl_xor(den[t], 16, 64);
        den[t] += __shfl_xor(den[t], 32, 64);
    }

    #pragma unroll
    for (int t = 0; t < 2; ++t) {
        #pragma unroll
        for (int k = 0; k < 4; ++k) {
            const int ro = g4 * 4 + k;
            const float dk = __shfl(den[t], ro, 64);
            const float z  = 1.0f / (dk + EPSF);
            const int l = l0 + t * 16 + ro;
            float* op = &Og[((size_t)(n * LLEN + l) * 8 + h) * 64 + r];
            #pragma unroll
            for (int u = 0; u < 4; ++u)
                op[u * 16] = acc[t][u][k] * z;
        }
    }
}

extern "C" void kernel_launch(void* const* d_in, const int* in_sizes, int n_in,
                              void* d_out, int out_size, void* d_ws, size_t ws_size,
                              hipStream_t stream) {
    const float* Q    = (const float*)d_in[0];
    const float* K    = (const float*)d_in[1];
    const float* V    = (const float*)d_in[2];
    const float* mask = (const float*)d_in[3];
    float* out = (float*)d_out;

    float* KVp   = (float*)d_ws;                              // [8][64][4096] f32 = 8 MB
    float* Ksump = KVp + (size_t)NSPLIT * NHTOT * 4096;       // [8][64][64]
    float* Ksum  = Ksump + (size_t)NSPLIT * NHTOT * 64;       // [64][64] f32
    short* KVThi = (short*)(Ksum + NHTOT * 64);               // [64][64m][64d] bf16
    short* KVTlo = KVThi + (size_t)NHTOT * 4096;
    // every ws element read is written first (no memset needed)

    dim3 g1(NSPLIT, NHTOT);
    la_phase1<<<g1, 256, 0, stream>>>(K, V, mask, KVp, Ksump);

    dim3 gr(4, NHTOT);
    la_reduce<<<gr, 256, 0, stream>>>(KVp, Ksump, KVThi, KVTlo, Ksum);

    dim3 g2(LLEN / 128, NHTOT);
    la_phase2<<<g2, 256, 0, stream>>>(Q, KVThi, KVTlo, Ksum, out);
}